// Round 3
// 1228.049 us; speedup vs baseline: 1.1461x; 1.1461x over previous
//
#include <hip/hip_runtime.h>

#define BROWS 32768

typedef _Float16 f16;
typedef __attribute__((ext_vector_type(8))) _Float16 f16x8;
typedef __attribute__((ext_vector_type(8))) short s16x8;
typedef __attribute__((ext_vector_type(4))) float f32x4;

enum { POST_NONE = 0, POST_RELU = 1, POST_EXP = 2, POST_SIG = 3 };

// Two-plane splits:
//  fp16 (encode path; values bounded ~O(3)): hi + lo/1024, rel err ~2^-22.
//  bf16 (decode path; z/h3 can reach O(1e5) -- fp16 would overflow to Inf,
//        and Inf*w + Inf*(-w) = NaN in MFMA, relu(NaN)=0 => the round-2 0.5
//        failure): hi + lo/256, rel err ~2^-16, range = fp32 range.
__device__ __forceinline__ unsigned short bf16_rne(float v) {
    unsigned u = __builtin_bit_cast(unsigned, v);
    u += 0x7fffu + ((u >> 16) & 1u);
    return (unsigned short)(u >> 16);
}
__device__ __forceinline__ float bf16_to_f(unsigned short h) {
    unsigned u = ((unsigned)h) << 16;
    return __builtin_bit_cast(float, u);
}
__device__ __forceinline__ float f16b_to_f(unsigned short b) {
    return (float)__builtin_bit_cast(f16, b);
}

template <bool BF16>
__device__ __forceinline__ void split2(float v, unsigned short& hi, unsigned short& lo) {
    if constexpr (BF16) {
        hi = bf16_rne(v);
        lo = bf16_rne((v - bf16_to_f(hi)) * 256.f);
    } else {
        const f16 h = (f16)v;
        hi = __builtin_bit_cast(unsigned short, h);
        lo = __builtin_bit_cast(unsigned short, (f16)((v - (float)h) * 1024.f));
    }
}
template <bool BF16>
__device__ __forceinline__ constexpr float inv_ls() { return BF16 ? (1.f / 256.f) : (1.f / 1024.f); }

template <bool BF16>
__device__ __forceinline__ f32x4 mfma16(s16x8 a, s16x8 b, f32x4 c) {
    if constexpr (BF16)
        return __builtin_amdgcn_mfma_f32_16x16x32_bf16(a, b, c, 0, 0, 0);
    else
        return __builtin_amdgcn_mfma_f32_16x16x32_f16(
            __builtin_bit_cast(f16x8, a), __builtin_bit_cast(f16x8, b), c, 0, 0, 0);
}

// zero the 64B spill pad after h1l (last-row K-spill reads must see 0, not
// possible-NaN garbage: NaN*0 = NaN in MFMA)
__global__ void zero_pad_kernel(unsigned short* p) { p[threadIdx.x] = 0; }

// W [K,N] f32 -> Wh/Wl [Npad][Kpad] planes (transposed to n-major, zero-padded).
// K-pad zeros are what make A-side garbage reads (row-pitch spill) harmless.
template <bool BF16>
__global__ __launch_bounds__(256) void split_w_kernel(
    const float* __restrict__ W, unsigned short* __restrict__ Wh,
    unsigned short* __restrict__ Wl, int K, int N, int Kpad, int Npad)
{
    const int i = blockIdx.x * 256 + threadIdx.x;
    if (i >= Npad * Kpad) return;
    const int n = i / Kpad, k = i - n * Kpad;
    const float v = (n < N && k < K) ? W[(size_t)k * N + n] : 0.f;
    split2<BF16>(v, Wh[i], Wl[i]);
}

// C[M,*] = post(A @ B + bias).  A: hi/lo planes [M,lda] (or inline-split fp32
// when AINLINE).  B: pre-split, pre-transposed planes [Npad][KPAD].
// K-loop runs to KPAD; A rows may be read past lda into the next row — fine,
// B planes are zero there.  3 passes: hi*hi -> acc1; hi*lo' + lo'*hi -> acc2.
// OUTMODE 0: fp32 C (cols < N).  OUTMODE 1: hi/lo planes, stride ldc=N.
template <int POST, int OUTMODE, bool AINLINE, bool BF16>
__global__ __launch_bounds__(256, 2) void gemm_2plane(
    const float* __restrict__ Af,
    const unsigned short* __restrict__ Ah, const unsigned short* __restrict__ Al,
    const unsigned short* __restrict__ Bh, const unsigned short* __restrict__ Bl,
    const float* __restrict__ bias,
    float* __restrict__ C, unsigned short* __restrict__ Ch, unsigned short* __restrict__ Cl,
    int N, int K, int KPAD, int lda, int ldc)
{
    // row stride 40 halves = 80B: 16B-aligned rows, bank period 8 -> ~2-way (free)
    __shared__ __align__(16) unsigned short As[2][128 * 40];
    __shared__ __align__(16) unsigned short Bs[2][128 * 40];

    const int t = threadIdx.x;
    const int row0 = blockIdx.y * 128;
    const int col0 = blockIdx.x * 128;

    const int wv = t >> 6, lane = t & 63;
    const int wr = (wv & 1) * 64, wc = (wv >> 1) * 64;   // wave 64x64 sub-tile
    const int l15 = lane & 15, quad = lane >> 4;

    const int sr = t >> 2, sk = (t & 3) * 8;   // plane staging: (row, 8-half strip)
    const int am = t >> 1, ak0 = (t & 1) * 16; // inline-A staging: (row, 16-f strip)

    f32x4 acc1[4][4] = {};
    f32x4 acc2[4][4] = {};

    for (int kt = 0; kt < KPAD; kt += 32) {
        // ---- global loads (no guards: B planes zero-padded, A spill benign) ----
        uint4 b0h, b0l, b1h, b1l;
        {
            const size_t o0 = (size_t)(col0 + sr) * KPAD + kt + sk;
            const size_t o1 = (size_t)(col0 + sr + 64) * KPAD + kt + sk;
            b0h = *(const uint4*)(Bh + o0); b1h = *(const uint4*)(Bh + o1);
            b0l = *(const uint4*)(Bl + o0); b1l = *(const uint4*)(Bl + o1);
        }
        uint4 a0h, a0l, a1h, a1l;
        float av[16];
        if constexpr (AINLINE) {
            const float* Arow = Af + (size_t)(row0 + am) * lda;
            if (kt + ak0 + 16 <= K) {
                const float4* Ap = (const float4*)(Arow + kt + ak0);
#pragma unroll
                for (int j = 0; j < 4; ++j) {
                    float4 q = Ap[j];
                    av[j * 4 + 0] = q.x; av[j * 4 + 1] = q.y;
                    av[j * 4 + 2] = q.z; av[j * 4 + 3] = q.w;
                }
            } else {
#pragma unroll
                for (int i = 0; i < 16; ++i) {
                    int k = kt + ak0 + i;
                    av[i] = (k < K) ? Arow[k] : 0.f;
                }
            }
        } else {
            const size_t o0 = (size_t)(row0 + sr) * lda + kt + sk;
            const size_t o1 = (size_t)(row0 + sr + 64) * lda + kt + sk;
            a0h = *(const uint4*)(Ah + o0); a1h = *(const uint4*)(Ah + o1);
            a0l = *(const uint4*)(Al + o0); a1l = *(const uint4*)(Al + o1);
        }

        __syncthreads();   // protect LDS from previous iteration's readers
        if constexpr (AINLINE) {
            union { unsigned short us[16]; uint4 q[2]; } uh, ul;
#pragma unroll
            for (int i = 0; i < 16; ++i)
                split2<BF16>(av[i], uh.us[i], ul.us[i]);
            *(uint4*)&As[0][am * 40 + ak0]     = uh.q[0];
            *(uint4*)&As[0][am * 40 + ak0 + 8] = uh.q[1];
            *(uint4*)&As[1][am * 40 + ak0]     = ul.q[0];
            *(uint4*)&As[1][am * 40 + ak0 + 8] = ul.q[1];
        } else {
            *(uint4*)&As[0][sr * 40 + sk]        = a0h;
            *(uint4*)&As[0][(sr + 64) * 40 + sk] = a1h;
            *(uint4*)&As[1][sr * 40 + sk]        = a0l;
            *(uint4*)&As[1][(sr + 64) * 40 + sk] = a1l;
        }
        *(uint4*)&Bs[0][sr * 40 + sk]        = b0h;
        *(uint4*)&Bs[0][(sr + 64) * 40 + sk] = b1h;
        *(uint4*)&Bs[1][sr * 40 + sk]        = b0l;
        *(uint4*)&Bs[1][(sr + 64) * 40 + sk] = b1l;
        __syncthreads();

        // ---- fragments + 3 MFMA passes (staged to cap frag liveness) ----
        s16x8 af0[4], bf0[4];
#pragma unroll
        for (int i = 0; i < 4; ++i) {
            af0[i] = *(const s16x8*)&As[0][(wr + i * 16 + l15) * 40 + quad * 8];
            bf0[i] = *(const s16x8*)&Bs[0][(wc + i * 16 + l15) * 40 + quad * 8];
        }
#pragma unroll
        for (int mt = 0; mt < 4; ++mt)
#pragma unroll
            for (int nt = 0; nt < 4; ++nt)
                acc1[mt][nt] = mfma16<BF16>(af0[mt], bf0[nt], acc1[mt][nt]);

        {
            s16x8 bf1[4];
#pragma unroll
            for (int i = 0; i < 4; ++i)
                bf1[i] = *(const s16x8*)&Bs[1][(wc + i * 16 + l15) * 40 + quad * 8];
#pragma unroll
            for (int mt = 0; mt < 4; ++mt)
#pragma unroll
                for (int nt = 0; nt < 4; ++nt)
                    acc2[mt][nt] = mfma16<BF16>(af0[mt], bf1[nt], acc2[mt][nt]);
        }
        {
            s16x8 af1[4];
#pragma unroll
            for (int i = 0; i < 4; ++i)
                af1[i] = *(const s16x8*)&As[1][(wr + i * 16 + l15) * 40 + quad * 8];
#pragma unroll
            for (int mt = 0; mt < 4; ++mt)
#pragma unroll
                for (int nt = 0; nt < 4; ++nt)
                    acc2[mt][nt] = mfma16<BF16>(af1[mt], bf0[nt], acc2[mt][nt]);
        }
    }

    // ---- epilogue: C/D map col=l15, row=quad*4+reg ----
#pragma unroll
    for (int nt = 0; nt < 4; ++nt) {
        const int col = col0 + wc + nt * 16 + l15;
        if (col < N) {
            const float bval = bias[col];
#pragma unroll
            for (int mt = 0; mt < 4; ++mt) {
                const int rbase = row0 + wr + mt * 16 + quad * 4;
#pragma unroll
                for (int r = 0; r < 4; ++r) {
                    float v = acc1[mt][nt][r] + acc2[mt][nt][r] * inv_ls<BF16>() + bval;
                    if (POST == POST_RELU) v = v > 0.f ? v : 0.f;
                    else if (POST == POST_EXP) v = expf(v);
                    else if (POST == POST_SIG) v = 1.f / (1.f + expf(-v));
                    if (OUTMODE == 0) {
                        C[(size_t)(rbase + r) * ldc + col] = v;
                    } else {
                        split2<BF16>(v, Ch[(size_t)(rbase + r) * ldc + col],
                                        Cl[(size_t)(rbase + r) * ldc + col]);
                    }
                }
            }
        }
    }
}

// one wave per row: a = softmax(h1@Wa + ba) in fp32 (h1 reconstructed from
// f16 planes, ~2^-22 accurate -> logit noise ~1e-7, idx-flip prob ~5e-4); idx
// via inverse CDF
__global__ __launch_bounds__(256) void a_idx_kernel(
    const unsigned short* __restrict__ h1h, const unsigned short* __restrict__ h1l,
    const float* __restrict__ Wa, const float* __restrict__ ba,
    const float* __restrict__ u, float* __restrict__ a_out,
    int* __restrict__ idx_out)
{
    const int r = blockIdx.x * 4 + (threadIdx.x >> 6);
    const int lane = threadIdx.x & 63;
    const unsigned short* hh = h1h + (size_t)r * 400;
    const unsigned short* hl = h1l + (size_t)r * 400;

    float acc0 = 0.f, acc1 = 0.f, acc2 = 0.f, acc3 = 0.f, acc4 = 0.f;
    for (int k = lane; k < 400; k += 64) {
        const float h = f16b_to_f(hh[k]) + f16b_to_f(hl[k]) * (1.f / 1024.f);
        const float* w = Wa + k * 5;
        acc0 += h * w[0]; acc1 += h * w[1]; acc2 += h * w[2];
        acc3 += h * w[3]; acc4 += h * w[4];
    }
    for (int off = 32; off; off >>= 1) {
        acc0 += __shfl_down(acc0, off);
        acc1 += __shfl_down(acc1, off);
        acc2 += __shfl_down(acc2, off);
        acc3 += __shfl_down(acc3, off);
        acc4 += __shfl_down(acc4, off);
    }
    if (lane == 0) {
        float l[5] = {acc0 + ba[0], acc1 + ba[1], acc2 + ba[2], acc3 + ba[3], acc4 + ba[4]};
        float mx = l[0];
        for (int n = 1; n < 5; ++n) mx = l[n] > mx ? l[n] : mx;
        float e[5], s = 0.f;
        for (int n = 0; n < 5; ++n) { e[n] = expf(l[n] - mx); s += e[n]; }
        const float inv = 1.f / s;
        const float uu = u[r];
        float cdf = 0.f;
        int idx = 0, found = 0;
        for (int n = 0; n < 5; ++n) {
            const float a = e[n] * inv;
            a_out[(size_t)r * 5 + n] = a;
            cdf += a;
            if (!found && uu < cdf) { idx = n; found = 1; }
        }
        idx_out[r] = idx;
    }
}

// one wave per row: solve Q w = eps (LU, partial pivot), z = Q @ (eigen*w) + mu
// writes z as BF16 hi/lo planes [r][32] (lanes 20..31 zero): z can reach O(1e5)
// on ill-conditioned rows -> fp16 would overflow, bf16 has fp32 range.
__global__ __launch_bounds__(256) void solve_kernel(
    const float* __restrict__ mu_o, const float* __restrict__ q_o,
    const float* __restrict__ e_o, const int* __restrict__ idxv,
    const float* __restrict__ eps,
    unsigned short* __restrict__ zh, unsigned short* __restrict__ zl)
{
    __shared__ float LU[4][20][21];
    __shared__ float Qo[4][20][21];
    __shared__ float rhs[4][20];
    __shared__ float wv[4][20];
    __shared__ float ew[4][20];

    const int wsl = threadIdx.x >> 6;
    const int lane = threadIdx.x & 63;
    const int r = blockIdx.x * 4 + wsl;

    const int idx = idxv[r];
    const float* Qp = q_o + (size_t)r * 2000 + idx * 400;
    for (int e = lane; e < 400; e += 64) {
        const float v = Qp[e];
        const int ri = e / 20, ci = e - ri * 20;
        LU[wsl][ri][ci] = v;
        Qo[wsl][ri][ci] = v;
    }
    if (lane < 20) rhs[wsl][lane] = eps[(size_t)r * 20 + lane];
    __syncthreads();

    for (int k = 0; k < 20; ++k) {
        float val = -1.f;
        int ii = k;
        if (lane >= k && lane < 20) { val = fabsf(LU[wsl][lane][k]); ii = lane; }
        for (int off = 32; off; off >>= 1) {
            const float ov = __shfl_down(val, off);
            const int oi = __shfl_down(ii, off);
            if (ov > val) { val = ov; ii = oi; }
        }
        const int piv = __shfl(ii, 0);
        if (piv != k) {
            if (lane < 20) {
                const float t1 = LU[wsl][k][lane], t2 = LU[wsl][piv][lane];
                LU[wsl][k][lane] = t2;
                LU[wsl][piv][lane] = t1;
            } else if (lane == 20) {
                const float t1 = rhs[wsl][k];
                rhs[wsl][k] = rhs[wsl][piv];
                rhs[wsl][piv] = t1;
            }
        }
        __syncthreads();
        const float pv = LU[wsl][k][k];
        if (lane > k && lane < 20) {
            const float m = LU[wsl][lane][k] / pv;
            for (int j = k + 1; j < 20; ++j)
                LU[wsl][lane][j] -= m * LU[wsl][k][j];
            rhs[wsl][lane] -= m * rhs[wsl][k];
        }
        __syncthreads();
    }

    for (int k = 19; k >= 0; --k) {
        const float wk = rhs[wsl][k] / LU[wsl][k][k];
        if (lane == 0) wv[wsl][k] = wk;
        if (lane < k) rhs[wsl][lane] -= LU[wsl][lane][k] * wk;
        __syncthreads();
    }

    if (lane < 20) {
        const float evl = e_o[(size_t)r * 100 + idx * 20 + lane];
        ew[wsl][lane] = evl * wv[wsl][lane];
    }
    __syncthreads();
    float zv = 0.f;
    if (lane < 20) {
        float acc = mu_o[(size_t)r * 100 + idx * 20 + lane];
        for (int j = 0; j < 20; ++j)
            acc += Qo[wsl][lane][j] * ew[wsl][j];
        zv = acc;
    }
    if (lane < 32) {
        split2<true>(zv, zh[(size_t)r * 32 + lane], zl[(size_t)r * 32 + lane]);
    }
}

extern "C" void kernel_launch(void* const* d_in, const int* in_sizes, int n_in,
                              void* d_out, int out_size, void* d_ws, size_t ws_size,
                              hipStream_t stream)
{
    const float* x   = (const float*)d_in[0];
    const float* u   = (const float*)d_in[1];
    const float* eps = (const float*)d_in[2];
    const float* W1  = (const float*)d_in[3];
    const float* b1  = (const float*)d_in[4];
    const float* Wmu = (const float*)d_in[5];
    const float* bmu = (const float*)d_in[6];
    const float* WQ  = (const float*)d_in[7];
    const float* bQ  = (const float*)d_in[8];
    const float* Wa  = (const float*)d_in[9];
    const float* ba  = (const float*)d_in[10];
    const float* We  = (const float*)d_in[11];
    const float* be  = (const float*)d_in[12];
    const float* W3  = (const float*)d_in[13];
    const float* b3  = (const float*)d_in[14];
    const float* W4  = (const float*)d_in[15];
    const float* b4  = (const float*)d_in[16];

    float* out   = (float*)d_out;
    float* recon = out;                                  // [B,784]
    float* mu_o  = out + (size_t)BROWS * 784;            // [B,100]
    float* q_o   = mu_o + (size_t)BROWS * 100;           // [B,2000]
    float* a_o   = q_o + (size_t)BROWS * 2000;           // [B,5]
    float* e_o   = a_o + (size_t)BROWS * 5;              // [B,100]

    typedef unsigned short us;

    // ---- workspace: ONLY what the final GEMM reads (h3 planes, W4 planes).
    // Total 53.9 MB — under the 55.2 MB the round-0 kernel proved available.
    char* p = (char*)d_ws;
    us* h1h = (us*)p; p += (size_t)BROWS * 400 * 2;       // h1 hi (reused as h3, bf16)
    us* h1l = (us*)p; p += (size_t)BROWS * 400 * 2;       // h1 lo (reused as h3, bf16)
    us* pad = (us*)p; p += 64;                            // zeroed 64B spill pad
    us* W4h = (us*)p; p += (size_t)896 * 416 * 2;
    us* W4l = (us*)p;

    // ---- everything consumed BEFORE the final GEMM lives in the recon output
    // region (B*784*4 = 102.8 MB, fully overwritten by the last dispatch).
    char* rs = (char*)recon;
    us* zh  = (us*)rs; rs += (size_t)BROWS * 32 * 2;
    us* zl  = (us*)rs; rs += (size_t)BROWS * 32 * 2;
    int* idx = (int*)rs; rs += (size_t)BROWS * 4;
    us* W1h = (us*)rs; rs += 512 * 800 * 2;
    us* W1l = (us*)rs; rs += 512 * 800 * 2;
    us* Wmuh = (us*)rs; rs += 128 * 416 * 2;
    us* Wmul = (us*)rs; rs += 128 * 416 * 2;
    us* WQh = (us*)rs; rs += 2048 * 416 * 2;
    us* WQl = (us*)rs; rs += 2048 * 416 * 2;
    us* Weh = (us*)rs; rs += 128 * 416 * 2;
    us* Wel = (us*)rs; rs += 128 * 416 * 2;
    us* W3h = (us*)rs; rs += 512 * 32 * 2;
    us* W3l = (us*)rs;

    const dim3 blk(256);
    const int my = BROWS / 128;  // 256
    auto cdiv = [](int a, int b) { return (a + b - 1) / b; };

    zero_pad_kernel<<<1, 32, 0, stream>>>(pad);

    // weight pre-split (transpose to [Npad][Kpad], zero-pad). Encode: fp16;
    // decode (W3, W4): bf16 for range safety.
    split_w_kernel<false><<<cdiv(512 * 800, 256), blk, 0, stream>>>(W1, W1h, W1l, 784, 400, 800, 512);
    split_w_kernel<false><<<cdiv(128 * 416, 256), blk, 0, stream>>>(Wmu, Wmuh, Wmul, 400, 100, 416, 128);
    split_w_kernel<false><<<cdiv(2048 * 416, 256), blk, 0, stream>>>(WQ, WQh, WQl, 400, 2000, 416, 2048);
    split_w_kernel<false><<<cdiv(128 * 416, 256), blk, 0, stream>>>(We, Weh, Wel, 400, 100, 416, 128);
    split_w_kernel<true><<<cdiv(512 * 32, 256), blk, 0, stream>>>(W3, W3h, W3l, 20, 400, 32, 512);
    split_w_kernel<true><<<cdiv(896 * 416, 256), blk, 0, stream>>>(W4, W4h, W4l, 400, 784, 416, 896);

    // encode (fp16 planes): h1 = relu(x@W1+b1), x split inline
    gemm_2plane<POST_RELU, 1, true, false><<<dim3(4, my), blk, 0, stream>>>(
        x, nullptr, nullptr, W1h, W1l, b1, nullptr, h1h, h1l, 400, 784, 800, 784, 400);
    gemm_2plane<POST_NONE, 0, false, false><<<dim3(1, my), blk, 0, stream>>>(
        nullptr, h1h, h1l, Wmuh, Wmul, bmu, mu_o, nullptr, nullptr, 100, 400, 416, 400, 100);
    gemm_2plane<POST_EXP, 0, false, false><<<dim3(16, my), blk, 0, stream>>>(
        nullptr, h1h, h1l, WQh, WQl, bQ, q_o, nullptr, nullptr, 2000, 400, 416, 400, 2000);
    gemm_2plane<POST_EXP, 0, false, false><<<dim3(1, my), blk, 0, stream>>>(
        nullptr, h1h, h1l, Weh, Wel, be, e_o, nullptr, nullptr, 100, 400, 416, 400, 100);
    a_idx_kernel<<<BROWS / 4, blk, 0, stream>>>(h1h, h1l, Wa, ba, u, a_o, idx);
    solve_kernel<<<BROWS / 4, blk, 0, stream>>>(mu_o, q_o, e_o, idx, eps, zh, zl);
    // decode (bf16 planes: z/h3 can be huge on ill-conditioned Q rows)
    gemm_2plane<POST_RELU, 1, false, true><<<dim3(4, my), blk, 0, stream>>>(
        nullptr, zh, zl, W3h, W3l, b3, nullptr, h1h, h1l, 400, 20, 32, 32, 400);
    gemm_2plane<POST_SIG, 0, false, true><<<dim3(7, my), blk, 0, stream>>>(
        nullptr, h1h, h1l, W4h, W4l, b4, recon, nullptr, nullptr, 784, 400, 416, 400, 784);
}

// Round 5
// 1112.225 us; speedup vs baseline: 1.2655x; 1.1041x over previous
//
#include <hip/hip_runtime.h>

#define BROWS 32768

typedef _Float16 f16;
typedef __attribute__((ext_vector_type(8))) _Float16 f16x8;
typedef __attribute__((ext_vector_type(8))) short s16x8;
typedef __attribute__((ext_vector_type(4))) float f32x4;

enum { POST_NONE = 0, POST_RELU = 1, POST_EXP = 2, POST_SIG = 3 };

// Two-plane splits:
//  fp16 (encode path; values bounded ~O(3)): hi + lo/1024, rel err ~2^-22.
//  bf16 (decode path; z/h3 can reach O(1e5) -- fp16 would overflow to Inf,
//        and Inf*w + Inf*(-w) = NaN in MFMA, relu(NaN)=0 => the round-2 0.5
//        failure): hi + lo/256, rel err ~2^-16, range = fp32 range.
__device__ __forceinline__ unsigned short bf16_rne(float v) {
    unsigned u = __builtin_bit_cast(unsigned, v);
    u += 0x7fffu + ((u >> 16) & 1u);
    return (unsigned short)(u >> 16);
}
__device__ __forceinline__ float bf16_to_f(unsigned short h) {
    unsigned u = ((unsigned)h) << 16;
    return __builtin_bit_cast(float, u);
}
__device__ __forceinline__ float f16b_to_f(unsigned short b) {
    return (float)__builtin_bit_cast(f16, b);
}

template <bool BF16>
__device__ __forceinline__ void split2(float v, unsigned short& hi, unsigned short& lo) {
    if constexpr (BF16) {
        hi = bf16_rne(v);
        lo = bf16_rne((v - bf16_to_f(hi)) * 256.f);
    } else {
        const f16 h = (f16)v;
        hi = __builtin_bit_cast(unsigned short, h);
        lo = __builtin_bit_cast(unsigned short, (f16)((v - (float)h) * 1024.f));
    }
}
template <bool BF16>
__device__ __forceinline__ constexpr float inv_ls() { return BF16 ? (1.f / 256.f) : (1.f / 1024.f); }

template <bool BF16>
__device__ __forceinline__ f32x4 mfma16(s16x8 a, s16x8 b, f32x4 c) {
    if constexpr (BF16)
        return __builtin_amdgcn_mfma_f32_16x16x32_bf16(a, b, c, 0, 0, 0);
    else
        return __builtin_amdgcn_mfma_f32_16x16x32_f16(
            __builtin_bit_cast(f16x8, a), __builtin_bit_cast(f16x8, b), c, 0, 0, 0);
}

// zero the 64B spill pad after h1l (last-row K-spill reads must see 0, not
// possible-NaN garbage: NaN*0 = NaN in MFMA)
__global__ void zero_pad_kernel(unsigned short* p) { p[threadIdx.x] = 0; }

// W [K,N] f32 -> Wh/Wl [Npad][Kpad] planes (transposed to n-major, zero-padded).
// K-pad zeros are what make A-side garbage reads (row-pitch spill) harmless.
template <bool BF16>
__global__ __launch_bounds__(256) void split_w_kernel(
    const float* __restrict__ W, unsigned short* __restrict__ Wh,
    unsigned short* __restrict__ Wl, int K, int N, int Kpad, int Npad)
{
    const int i = blockIdx.x * 256 + threadIdx.x;
    if (i >= Npad * Kpad) return;
    const int n = i / Kpad, k = i - n * Kpad;
    const float v = (n < N && k < K) ? W[(size_t)k * N + n] : 0.f;
    split2<BF16>(v, Wh[i], Wl[i]);
}

// C[M,*] = post(A @ B + bias).  A: hi/lo planes [M,lda] (or inline-split fp32
// when AINLINE).  B: pre-split, pre-transposed planes [Npad][KPAD].
// K-loop runs to KPAD; A rows may be read past lda into the next row — fine,
// B planes are zero there.  3 passes: hi*hi -> acc1; hi*lo' + lo'*hi -> acc2.
// OUTMODE 0: fp32 C (cols < N).  OUTMODE 1: hi/lo planes, stride ldc=N.
template <int POST, int OUTMODE, bool AINLINE, bool BF16>
__global__ __launch_bounds__(256, 2) void gemm_2plane(
    const float* __restrict__ Af,
    const unsigned short* __restrict__ Ah, const unsigned short* __restrict__ Al,
    const unsigned short* __restrict__ Bh, const unsigned short* __restrict__ Bl,
    const float* __restrict__ bias,
    float* __restrict__ C, unsigned short* __restrict__ Ch, unsigned short* __restrict__ Cl,
    int N, int K, int KPAD, int lda, int ldc)
{
    // row stride 40 halves = 80B: 16B-aligned rows, bank period 8 -> ~2-way (free)
    __shared__ __align__(16) unsigned short As[2][128 * 40];
    __shared__ __align__(16) unsigned short Bs[2][128 * 40];

    const int t = threadIdx.x;
    const int row0 = blockIdx.y * 128;
    const int col0 = blockIdx.x * 128;

    const int wv = t >> 6, lane = t & 63;
    const int wr = (wv & 1) * 64, wc = (wv >> 1) * 64;   // wave 64x64 sub-tile
    const int l15 = lane & 15, quad = lane >> 4;

    const int sr = t >> 2, sk = (t & 3) * 8;   // plane staging: (row, 8-half strip)
    const int am = t >> 1, ak0 = (t & 1) * 16; // inline-A staging: (row, 16-f strip)

    f32x4 acc1[4][4] = {};
    f32x4 acc2[4][4] = {};

    for (int kt = 0; kt < KPAD; kt += 32) {
        // ---- global loads (no guards: B planes zero-padded, A spill benign) ----
        uint4 b0h, b0l, b1h, b1l;
        {
            const size_t o0 = (size_t)(col0 + sr) * KPAD + kt + sk;
            const size_t o1 = (size_t)(col0 + sr + 64) * KPAD + kt + sk;
            b0h = *(const uint4*)(Bh + o0); b1h = *(const uint4*)(Bh + o1);
            b0l = *(const uint4*)(Bl + o0); b1l = *(const uint4*)(Bl + o1);
        }
        uint4 a0h, a0l, a1h, a1l;
        float av[16];
        if constexpr (AINLINE) {
            const float* Arow = Af + (size_t)(row0 + am) * lda;
            if (kt + ak0 + 16 <= K) {
                const float4* Ap = (const float4*)(Arow + kt + ak0);
#pragma unroll
                for (int j = 0; j < 4; ++j) {
                    float4 q = Ap[j];
                    av[j * 4 + 0] = q.x; av[j * 4 + 1] = q.y;
                    av[j * 4 + 2] = q.z; av[j * 4 + 3] = q.w;
                }
            } else {
#pragma unroll
                for (int i = 0; i < 16; ++i) {
                    int k = kt + ak0 + i;
                    av[i] = (k < K) ? Arow[k] : 0.f;
                }
            }
        } else {
            const size_t o0 = (size_t)(row0 + sr) * lda + kt + sk;
            const size_t o1 = (size_t)(row0 + sr + 64) * lda + kt + sk;
            a0h = *(const uint4*)(Ah + o0); a1h = *(const uint4*)(Ah + o1);
            a0l = *(const uint4*)(Al + o0); a1l = *(const uint4*)(Al + o1);
        }

        __syncthreads();   // protect LDS from previous iteration's readers
        if constexpr (AINLINE) {
            union { unsigned short us[16]; uint4 q[2]; } uh, ul;
#pragma unroll
            for (int i = 0; i < 16; ++i)
                split2<BF16>(av[i], uh.us[i], ul.us[i]);
            *(uint4*)&As[0][am * 40 + ak0]     = uh.q[0];
            *(uint4*)&As[0][am * 40 + ak0 + 8] = uh.q[1];
            *(uint4*)&As[1][am * 40 + ak0]     = ul.q[0];
            *(uint4*)&As[1][am * 40 + ak0 + 8] = ul.q[1];
        } else {
            *(uint4*)&As[0][sr * 40 + sk]        = a0h;
            *(uint4*)&As[0][(sr + 64) * 40 + sk] = a1h;
            *(uint4*)&As[1][sr * 40 + sk]        = a0l;
            *(uint4*)&As[1][(sr + 64) * 40 + sk] = a1l;
        }
        *(uint4*)&Bs[0][sr * 40 + sk]        = b0h;
        *(uint4*)&Bs[0][(sr + 64) * 40 + sk] = b1h;
        *(uint4*)&Bs[1][sr * 40 + sk]        = b0l;
        *(uint4*)&Bs[1][(sr + 64) * 40 + sk] = b1l;
        __syncthreads();

        // ---- fragments + 3 MFMA passes (staged to cap frag liveness) ----
        s16x8 af0[4], bf0[4];
#pragma unroll
        for (int i = 0; i < 4; ++i) {
            af0[i] = *(const s16x8*)&As[0][(wr + i * 16 + l15) * 40 + quad * 8];
            bf0[i] = *(const s16x8*)&Bs[0][(wc + i * 16 + l15) * 40 + quad * 8];
        }
#pragma unroll
        for (int mt = 0; mt < 4; ++mt)
#pragma unroll
            for (int nt = 0; nt < 4; ++nt)
                acc1[mt][nt] = mfma16<BF16>(af0[mt], bf0[nt], acc1[mt][nt]);

        {
            s16x8 bf1[4];
#pragma unroll
            for (int i = 0; i < 4; ++i)
                bf1[i] = *(const s16x8*)&Bs[1][(wc + i * 16 + l15) * 40 + quad * 8];
#pragma unroll
            for (int mt = 0; mt < 4; ++mt)
#pragma unroll
                for (int nt = 0; nt < 4; ++nt)
                    acc2[mt][nt] = mfma16<BF16>(af0[mt], bf1[nt], acc2[mt][nt]);
        }
        {
            s16x8 af1[4];
#pragma unroll
            for (int i = 0; i < 4; ++i)
                af1[i] = *(const s16x8*)&As[1][(wr + i * 16 + l15) * 40 + quad * 8];
#pragma unroll
            for (int mt = 0; mt < 4; ++mt)
#pragma unroll
                for (int nt = 0; nt < 4; ++nt)
                    acc2[mt][nt] = mfma16<BF16>(af1[mt], bf0[nt], acc2[mt][nt]);
        }
    }

    // ---- epilogue: C/D map col=l15, row=quad*4+reg ----
#pragma unroll
    for (int nt = 0; nt < 4; ++nt) {
        const int col = col0 + wc + nt * 16 + l15;
        if (col < N) {
            const float bval = bias[col];
#pragma unroll
            for (int mt = 0; mt < 4; ++mt) {
                const int rbase = row0 + wr + mt * 16 + quad * 4;
#pragma unroll
                for (int r = 0; r < 4; ++r) {
                    float v = acc1[mt][nt][r] + acc2[mt][nt][r] * inv_ls<BF16>() + bval;
                    if (POST == POST_RELU) v = v > 0.f ? v : 0.f;
                    else if (POST == POST_EXP) v = expf(v);
                    else if (POST == POST_SIG) v = 1.f / (1.f + expf(-v));
                    if (OUTMODE == 0) {
                        C[(size_t)(rbase + r) * ldc + col] = v;
                    } else {
                        split2<BF16>(v, Ch[(size_t)(rbase + r) * ldc + col],
                                        Cl[(size_t)(rbase + r) * ldc + col]);
                    }
                }
            }
        }
    }
}

// one wave per row: a = softmax(h1@Wa + ba) in fp32 (h1 reconstructed from
// f16 planes, ~2^-22 accurate -> logit noise ~1e-7, idx-flip prob ~5e-4); idx
// via inverse CDF
__global__ __launch_bounds__(256) void a_idx_kernel(
    const unsigned short* __restrict__ h1h, const unsigned short* __restrict__ h1l,
    const float* __restrict__ Wa, const float* __restrict__ ba,
    const float* __restrict__ u, float* __restrict__ a_out,
    int* __restrict__ idx_out)
{
    const int r = blockIdx.x * 4 + (threadIdx.x >> 6);
    const int lane = threadIdx.x & 63;
    const unsigned short* hh = h1h + (size_t)r * 400;
    const unsigned short* hl = h1l + (size_t)r * 400;

    float acc0 = 0.f, acc1 = 0.f, acc2 = 0.f, acc3 = 0.f, acc4 = 0.f;
    for (int k = lane; k < 400; k += 64) {
        const float h = f16b_to_f(hh[k]) + f16b_to_f(hl[k]) * (1.f / 1024.f);
        const float* w = Wa + k * 5;
        acc0 += h * w[0]; acc1 += h * w[1]; acc2 += h * w[2];
        acc3 += h * w[3]; acc4 += h * w[4];
    }
    for (int off = 32; off; off >>= 1) {
        acc0 += __shfl_down(acc0, off);
        acc1 += __shfl_down(acc1, off);
        acc2 += __shfl_down(acc2, off);
        acc3 += __shfl_down(acc3, off);
        acc4 += __shfl_down(acc4, off);
    }
    if (lane == 0) {
        float l[5] = {acc0 + ba[0], acc1 + ba[1], acc2 + ba[2], acc3 + ba[3], acc4 + ba[4]};
        float mx = l[0];
        for (int n = 1; n < 5; ++n) mx = l[n] > mx ? l[n] : mx;
        float e[5], s = 0.f;
        for (int n = 0; n < 5; ++n) { e[n] = expf(l[n] - mx); s += e[n]; }
        const float inv = 1.f / s;
        const float uu = u[r];
        float cdf = 0.f;
        int idx = 0, found = 0;
        for (int n = 0; n < 5; ++n) {
            const float a = e[n] * inv;
            a_out[(size_t)r * 5 + n] = a;
            cdf += a;
            if (!found && uu < cdf) { idx = n; found = 1; }
        }
        idx_out[r] = idx;
    }
}

// one wave per system, barrier-free, LDS-free: lane l holds row l of Q in
// registers (fully unrolled -> static indexing only).  Gauss-Jordan with
// pivoting-by-indirection (no row swaps): per step, argmax|col k| over unused
// lanes via packed-int butterfly (6 shuffles: |a_k| bits monotone, low 5 bits
// = lane), broadcast pivot row via __shfl, uniform normalize/eliminate.
// Lane p remembers its solution column (mycol); a ds_permute push-scatter
// reorders rhs into column order at the end.  z = Q @ (e*w) + mu via 20
// static-lane broadcasts.  z stored as BF16 planes (fp16 would overflow:
// z can reach O(1e5) on ill-conditioned rows -- the round-2 lesson).
__global__ __launch_bounds__(256) void solve_kernel(
    const float* __restrict__ mu_o, const float* __restrict__ q_o,
    const float* __restrict__ e_o, const int* __restrict__ idxv,
    const float* __restrict__ eps,
    unsigned short* __restrict__ zh, unsigned short* __restrict__ zl)
{
    const int wsl = threadIdx.x >> 6;
    const int lane = threadIdx.x & 63;
    const int r = blockIdx.x * 4 + wsl;
    const int idx = idxv[r];
    const bool rowok = lane < 20;

    const float* Qp = q_o + (size_t)r * 2000 + idx * 400;

    float a[20];    // working row (lane l holds row l)
    float qc[20];   // untouched copy of Q row (for the final P V P^-1 apply)
    float rhs;
    if (rowok) {
        const float4* q4 = (const float4*)(Qp + lane * 20);
#pragma unroll
        for (int j = 0; j < 5; ++j) {
            float4 v = q4[j];
            a[j * 4 + 0] = v.x; a[j * 4 + 1] = v.y;
            a[j * 4 + 2] = v.z; a[j * 4 + 3] = v.w;
        }
#pragma unroll
        for (int j = 0; j < 20; ++j) qc[j] = a[j];
        rhs = eps[(size_t)r * 20 + lane];
    } else {
#pragma unroll
        for (int j = 0; j < 20; ++j) { a[j] = 0.f; qc[j] = 0.f; }
        rhs = 0.f;
    }

    bool used = !rowok;
    int mycol = lane;   // pivot lane p_k records k; scatter key for w-reorder

#pragma unroll
    for (int k = 0; k < 20; ++k) {
        // pivot = argmax |a[k]| over unused lanes (packed-int trick: fabs
        // bits are monotone as signed int; ineligible lanes pack negative)
        const float cand = used ? -1.f : fabsf(a[k]);
        int packed = (__builtin_bit_cast(int, cand) & ~31) | lane;
#pragma unroll
        for (int off = 32; off; off >>= 1) {
            const int o = __shfl_xor(packed, off);
            packed = o > packed ? o : packed;
        }
        const int p = packed & 31;
        const float pv = __shfl(a[k], p);
        const float rpv = 1.f / pv;
        const bool isp = (lane == p);
        if (isp) { used = true; mycol = k; }
        // lane p: row *= rpv (normalize); others: row -= (a_k*rpv) * pivot row
        const float f = isp ? 0.f : a[k] * rpv;
        const float s = isp ? rpv : 1.f;
#pragma unroll
        for (int j = k + 1; j < 20; ++j) {
            const float pr = __shfl(a[j], p);
            a[j] = a[j] * s - f * pr;
        }
        const float prr = __shfl(rhs, p);
        rhs = rhs * s - f * prr;
    }

    // rhs at lane p_k is x_k; push-scatter so lane k holds w[k]
    const int wbits = __builtin_amdgcn_ds_permute(
        mycol << 2, __builtin_bit_cast(int, rhs));
    const float w_l = __builtin_bit_cast(float, wbits);

    const float e_l  = rowok ? e_o[(size_t)r * 100 + idx * 20 + lane] : 0.f;
    const float mu_l = rowok ? mu_o[(size_t)r * 100 + idx * 20 + lane] : 0.f;
    const float ew_l = e_l * w_l;

    float z = mu_l;
#pragma unroll
    for (int k = 0; k < 20; ++k)
        z += qc[k] * __shfl(ew_l, k);

    if (lane < 32) {
        const float zv = rowok ? z : 0.f;
        split2<true>(zv, zh[(size_t)r * 32 + lane], zl[(size_t)r * 32 + lane]);
    }
}

extern "C" void kernel_launch(void* const* d_in, const int* in_sizes, int n_in,
                              void* d_out, int out_size, void* d_ws, size_t ws_size,
                              hipStream_t stream)
{
    const float* x   = (const float*)d_in[0];
    const float* u   = (const float*)d_in[1];
    const float* eps = (const float*)d_in[2];
    const float* W1  = (const float*)d_in[3];
    const float* b1  = (const float*)d_in[4];
    const float* Wmu = (const float*)d_in[5];
    const float* bmu = (const float*)d_in[6];
    const float* WQ  = (const float*)d_in[7];
    const float* bQ  = (const float*)d_in[8];
    const float* Wa  = (const float*)d_in[9];
    const float* ba  = (const float*)d_in[10];
    const float* We  = (const float*)d_in[11];
    const float* be  = (const float*)d_in[12];
    const float* W3  = (const float*)d_in[13];
    const float* b3  = (const float*)d_in[14];
    const float* W4  = (const float*)d_in[15];
    const float* b4  = (const float*)d_in[16];

    float* out   = (float*)d_out;
    float* recon = out;                                  // [B,784]
    float* mu_o  = out + (size_t)BROWS * 784;            // [B,100]
    float* q_o   = mu_o + (size_t)BROWS * 100;           // [B,2000]
    float* a_o   = q_o + (size_t)BROWS * 2000;           // [B,5]
    float* e_o   = a_o + (size_t)BROWS * 5;              // [B,100]

    typedef unsigned short us;

    // ---- workspace: ONLY what the final GEMM reads (h3 planes, W4 planes).
    // Total 53.9 MB — under the 55.2 MB the round-0 kernel proved available.
    char* p = (char*)d_ws;
    us* h1h = (us*)p; p += (size_t)BROWS * 400 * 2;       // h1 hi (reused as h3, bf16)
    us* h1l = (us*)p; p += (size_t)BROWS * 400 * 2;       // h1 lo (reused as h3, bf16)
    us* pad = (us*)p; p += 64;                            // zeroed 64B spill pad
    us* W4h = (us*)p; p += (size_t)896 * 416 * 2;
    us* W4l = (us*)p;

    // ---- everything consumed BEFORE the final GEMM lives in the recon output
    // region (B*784*4 = 102.8 MB, fully overwritten by the last dispatch).
    char* rs = (char*)recon;
    us* zh  = (us*)rs; rs += (size_t)BROWS * 32 * 2;
    us* zl  = (us*)rs; rs += (size_t)BROWS * 32 * 2;
    int* idx = (int*)rs; rs += (size_t)BROWS * 4;
    us* W1h = (us*)rs; rs += 512 * 800 * 2;
    us* W1l = (us*)rs; rs += 512 * 800 * 2;
    us* Wmuh = (us*)rs; rs += 128 * 416 * 2;
    us* Wmul = (us*)rs; rs += 128 * 416 * 2;
    us* WQh = (us*)rs; rs += 2048 * 416 * 2;
    us* WQl = (us*)rs; rs += 2048 * 416 * 2;
    us* Weh = (us*)rs; rs += 128 * 416 * 2;
    us* Wel = (us*)rs; rs += 128 * 416 * 2;
    us* W3h = (us*)rs; rs += 512 * 32 * 2;
    us* W3l = (us*)rs;

    const dim3 blk(256);
    const int my = BROWS / 128;  // 256
    auto cdiv = [](int a, int b) { return (a + b - 1) / b; };

    zero_pad_kernel<<<1, 32, 0, stream>>>(pad);

    // weight pre-split (transpose to [Npad][Kpad], zero-pad). Encode: fp16;
    // decode (W3, W4): bf16 for range safety.
    split_w_kernel<false><<<cdiv(512 * 800, 256), blk, 0, stream>>>(W1, W1h, W1l, 784, 400, 800, 512);
    split_w_kernel<false><<<cdiv(128 * 416, 256), blk, 0, stream>>>(Wmu, Wmuh, Wmul, 400, 100, 416, 128);
    split_w_kernel<false><<<cdiv(2048 * 416, 256), blk, 0, stream>>>(WQ, WQh, WQl, 400, 2000, 416, 2048);
    split_w_kernel<false><<<cdiv(128 * 416, 256), blk, 0, stream>>>(We, Weh, Wel, 400, 100, 416, 128);
    split_w_kernel<true><<<cdiv(512 * 32, 256), blk, 0, stream>>>(W3, W3h, W3l, 20, 400, 32, 512);
    split_w_kernel<true><<<cdiv(896 * 416, 256), blk, 0, stream>>>(W4, W4h, W4l, 400, 784, 416, 896);

    // encode (fp16 planes): h1 = relu(x@W1+b1), x split inline
    gemm_2plane<POST_RELU, 1, true, false><<<dim3(4, my), blk, 0, stream>>>(
        x, nullptr, nullptr, W1h, W1l, b1, nullptr, h1h, h1l, 400, 784, 800, 784, 400);
    gemm_2plane<POST_NONE, 0, false, false><<<dim3(1, my), blk, 0, stream>>>(
        nullptr, h1h, h1l, Wmuh, Wmul, bmu, mu_o, nullptr, nullptr, 100, 400, 416, 400, 100);
    gemm_2plane<POST_EXP, 0, false, false><<<dim3(16, my), blk, 0, stream>>>(
        nullptr, h1h, h1l, WQh, WQl, bQ, q_o, nullptr, nullptr, 2000, 400, 416, 400, 2000);
    gemm_2plane<POST_EXP, 0, false, false><<<dim3(1, my), blk, 0, stream>>>(
        nullptr, h1h, h1l, Weh, Wel, be, e_o, nullptr, nullptr, 100, 400, 416, 400, 100);
    a_idx_kernel<<<BROWS / 4, blk, 0, stream>>>(h1h, h1l, Wa, ba, u, a_o, idx);
    solve_kernel<<<BROWS / 4, blk, 0, stream>>>(mu_o, q_o, e_o, idx, eps, zh, zl);
    // decode (bf16 planes: z/h3 can be huge on ill-conditioned Q rows)
    gemm_2plane<POST_RELU, 1, false, true><<<dim3(4, my), blk, 0, stream>>>(
        nullptr, zh, zl, W3h, W3l, b3, nullptr, h1h, h1l, 400, 20, 32, 32, 400);
    gemm_2plane<POST_SIG, 0, false, true><<<dim3(7, my), blk, 0, stream>>>(
        nullptr, h1h, h1l, W4h, W4l, b4, recon, nullptr, nullptr, 784, 400, 416, 400, 784);
}